// Round 1
// baseline (1592.432 us; speedup 1.0000x reference)
//
#include <hip/hip_runtime.h>

#define NN   50000
#define NPAD 50048           // 782 * 64
#define EE   600000
#define DD   128
#define HH   256
#define LL   5
#define BN_EPS 1e-5f
#define SCAN_BLOCKS 196      // ceil(NN/256)

// ---------------- input projection: h = x @ Wx + bx ----------------
__global__ void proj_x_kernel(const float* __restrict__ x, const float* __restrict__ Wx,
                              const float* __restrict__ bx, float* __restrict__ h)
{
    int idx = blockIdx.x * 256 + threadIdx.x;
    if (idx >= NN * DD) return;
    int n = idx >> 7, d = idx & 127;
    const float* xr = x + (size_t)n * 78;
    float acc = bx[d];
#pragma unroll
    for (int k = 0; k < 78; k++) acc = fmaf(xr[k], Wx[k * DD + d], acc);
    h[idx] = acc;
}

// ------------- per-node edge-attr sums, degree, counts -------------
__global__ void edge_stats_kernel(const float* __restrict__ ea, const int* __restrict__ ei,
                                  float* __restrict__ s7, float* __restrict__ degf,
                                  int* __restrict__ counts)
{
    int e = blockIdx.x * 256 + threadIdx.x;
    if (e >= EE) return;
    int dst = ei[EE + e];
#pragma unroll
    for (int k = 0; k < 7; k++) atomicAdd(&s7[dst * 8 + k], ea[(size_t)e * 7 + k]);
    atomicAdd(&degf[dst], 1.0f);
    atomicAdd(&counts[dst], 1);
}

// ---------------- 3-phase exclusive scan for CSR rowptr ----------------
__global__ void count_scan1(const int* __restrict__ counts, int* __restrict__ rowptr,
                            int* __restrict__ blocksums)
{
    __shared__ int buf[256];
    int i = blockIdx.x * 256 + threadIdx.x;
    int v = (i < NN) ? counts[i] : 0;
    int val = v;
    buf[threadIdx.x] = val;
    __syncthreads();
    for (int off = 1; off < 256; off <<= 1) {
        int t = (threadIdx.x >= off) ? buf[threadIdx.x - off] : 0;
        __syncthreads();
        val += t;
        buf[threadIdx.x] = val;
        __syncthreads();
    }
    if (i < NN) rowptr[i] = val - v;          // block-local exclusive
    if (threadIdx.x == 255) blocksums[blockIdx.x] = val;
}

__global__ void count_scan2(int* __restrict__ blocksums, int* __restrict__ rowptr)
{
    __shared__ int buf[256];
    int v = (threadIdx.x < SCAN_BLOCKS) ? blocksums[threadIdx.x] : 0;
    int val = v;
    buf[threadIdx.x] = val;
    __syncthreads();
    for (int off = 1; off < 256; off <<= 1) {
        int t = (threadIdx.x >= off) ? buf[threadIdx.x - off] : 0;
        __syncthreads();
        val += t;
        buf[threadIdx.x] = val;
        __syncthreads();
    }
    if (threadIdx.x < SCAN_BLOCKS) blocksums[threadIdx.x] = val - v;  // exclusive block offsets
    if (threadIdx.x == 255) rowptr[NN] = val;                         // total == EE
}

__global__ void count_scan3(const int* __restrict__ blocksums, int* __restrict__ rowptr,
                            int* __restrict__ cursor)
{
    int i = blockIdx.x * 256 + threadIdx.x;
    if (i < NN) {
        int r = rowptr[i] + blocksums[blockIdx.x];
        rowptr[i] = r;
        cursor[i] = r;
    }
}

__global__ void csr_fill_kernel(const int* __restrict__ ei, int* __restrict__ cursor,
                                int* __restrict__ csr_src)
{
    int e = blockIdx.x * 256 + threadIdx.x;
    if (e >= EE) return;
    int dst = ei[EE + e];
    int pos = atomicAdd(&cursor[dst], 1);
    csr_src[pos] = ei[e];      // store source node id directly
}

// --------- per-layer aggregation: agg[n] = sum_in h[src] + s7[n]@We + deg*be ---------
__global__ __launch_bounds__(256) void aggregate_kernel(
    const float* __restrict__ h, const int* __restrict__ rowptr,
    const int* __restrict__ csr_src, const float* __restrict__ s7,
    const float* __restrict__ degf, const float* __restrict__ We,
    const float* __restrict__ be, float* __restrict__ agg)
{
    __shared__ float sWe[7 * DD];
    for (int i = threadIdx.x; i < 7 * DD; i += 256) sWe[i] = We[i];
    __syncthreads();
    int n = blockIdx.x * 4 + (threadIdx.x >> 6);   // 12500 blocks * 4 waves == NN
    int lane = threadIdx.x & 63;
    if (n >= NN) return;
    int beg = rowptr[n], end = rowptr[n + 1];
    float a0 = 0.f, a1 = 0.f;
    for (int i = beg; i < end; i++) {
        const float* hr = h + (size_t)csr_src[i] * DD;
        a0 += hr[lane];
        a1 += hr[lane + 64];
    }
    float dg = degf[n];
    float b0 = dg * be[lane], b1 = dg * be[lane + 64];
#pragma unroll
    for (int k = 0; k < 7; k++) {
        float sv = s7[n * 8 + k];
        b0 = fmaf(sv, sWe[k * DD + lane], b0);
        b1 = fmaf(sv, sWe[k * DD + lane + 64], b1);
    }
    agg[(size_t)n * DD + lane]      = a0 + b0;
    agg[(size_t)n * DD + 64 + lane] = a1 + b1;
}

// ---------------- tiled fp32 GEMM: C[M,Nn] = A[M,K] @ B[K,Nn] + bias (+ReLU) ----------------
// BM=BN=64, BK=16, 256 threads, 4x4 micro-tile. M fixed = NPAD (divisible by 64).
__global__ __launch_bounds__(256) void gemm_kernel(const float* __restrict__ A,
    const float* __restrict__ B, const float* __restrict__ bias,
    float* __restrict__ C, int K, int Nn, int relu)
{
    __shared__ float As[16][64];   // transposed A tile: As[k][m]
    __shared__ float Bs[16][64];
    const int tid = threadIdx.x;
    const int tx = tid & 15, ty = tid >> 4;
    const int row0 = blockIdx.x * 64, col0 = blockIdx.y * 64;
    const int la_r = tid >> 2, la_k = (tid & 3) * 4;
    const int lb_k = tid >> 4, lb_c = (tid & 15) * 4;
    float c[4][4] = {};
    for (int k0 = 0; k0 < K; k0 += 16) {
        float4 av = *(const float4*)(A + (size_t)(row0 + la_r) * K + (k0 + la_k));
        float4 bv = *(const float4*)(B + (size_t)(k0 + lb_k) * Nn + (col0 + lb_c));
        As[la_k + 0][la_r] = av.x;
        As[la_k + 1][la_r] = av.y;
        As[la_k + 2][la_r] = av.z;
        As[la_k + 3][la_r] = av.w;
        *(float4*)&Bs[lb_k][lb_c] = bv;
        __syncthreads();
#pragma unroll
        for (int kk = 0; kk < 16; kk++) {
            float4 a4 = *(const float4*)&As[kk][ty * 4];
            float4 b4 = *(const float4*)&Bs[kk][tx * 4];
            float ar[4] = {a4.x, a4.y, a4.z, a4.w};
            float br[4] = {b4.x, b4.y, b4.z, b4.w};
#pragma unroll
            for (int i = 0; i < 4; i++)
#pragma unroll
                for (int j = 0; j < 4; j++)
                    c[i][j] = fmaf(ar[i], br[j], c[i][j]);
        }
        __syncthreads();
    }
#pragma unroll
    for (int i = 0; i < 4; i++) {
        int r = row0 + ty * 4 + i;
#pragma unroll
        for (int j = 0; j < 4; j++) {
            int cc = col0 + tx * 4 + j;
            float v = c[i][j] + bias[cc];
            if (relu) v = fmaxf(v, 0.0f);
            C[(size_t)r * Nn + cc] = v;
        }
    }
}

// ---------------- BatchNorm statistics (column sums over NN rows) ----------------
__global__ void bn_stats_kernel(const float* __restrict__ z, float* __restrict__ sums)
{
    int gtid = blockIdx.x * 256 + threadIdx.x;    // 256 blocks -> 512 row streams
    int d = gtid & 127;
    float s = 0.f, s2 = 0.f;
    for (int n = gtid >> 7; n < NN; n += 512) {
        float v = z[(size_t)n * DD + d];
        s += v;
        s2 = fmaf(v, v, s2);
    }
    atomicAdd(&sums[d], s);
    atomicAdd(&sums[DD + d], s2);
}

__global__ void bn_finalize_kernel(const float* __restrict__ sums, const float* __restrict__ gamma,
                                   const float* __restrict__ beta, float* __restrict__ ab)
{
    int d = threadIdx.x;
    float mu  = sums[d] * (1.0f / NN);
    float var = sums[DD + d] * (1.0f / NN) - mu * mu;
    float inv = 1.0f / sqrtf(var + BN_EPS);
    float a = gamma[d] * inv;
    ab[d]      = a;
    ab[DD + d] = beta[d] - mu * a;
}

__global__ void bn_apply_kernel(const float* __restrict__ z, const float* __restrict__ ab,
                                float* __restrict__ out, int relu)
{
    int idx = blockIdx.x * 256 + threadIdx.x;
    if (idx >= NN * DD) return;
    int d = idx & 127;
    float v = fmaf(ab[d], z[idx], ab[DD + d]);
    if (relu) v = fmaxf(v, 0.f);
    out[idx] = v;
}

// ---------------------------------------------------------------------------
extern "C" void kernel_launch(void* const* d_in, const int* in_sizes, int n_in,
                              void* d_out, int out_size, void* d_ws, size_t ws_size,
                              hipStream_t stream)
{
    const float* x     = (const float*)d_in[0];
    const float* ea    = (const float*)d_in[1];
    const float* Wx    = (const float*)d_in[2];
    const float* bx    = (const float*)d_in[3];
    const float* We    = (const float*)d_in[4];
    const float* be    = (const float*)d_in[5];
    const float* W1    = (const float*)d_in[6];
    const float* b1    = (const float*)d_in[7];
    const float* W2    = (const float*)d_in[8];
    const float* b2    = (const float*)d_in[9];
    const float* gamma = (const float*)d_in[10];
    const float* beta  = (const float*)d_in[11];
    const int*   ei    = (const int*)d_in[12];

    // ---- workspace layout (floats first, then ints) ----
    float* fws = (float*)d_ws;
    size_t off = 0;
    float* h    = fws + off; off += (size_t)NPAD * DD;    // 6,406,144
    float* az   = fws + off; off += (size_t)NPAD * DD;    // agg / z shared
    float* z1   = fws + off; off += (size_t)NPAD * HH;    // hidden
    float* s7   = fws + off; off += (size_t)NN * 8;       // per-node edge-attr sums (padded to 8)
    float* degf = fws + off; off += 50048;                // degree (float), adjacent to s7
    float* sums = fws + off; off += 256;                  // bn sum / sumsq
    float* ab   = fws + off; off += 256;                  // bn scale / shift
    int* iws       = (int*)(fws + off);
    int* counts    = iws;                  // 50048
    int* rowptr    = counts + 50048;       // 50056 (NN+1 used)
    int* cursor    = rowptr + 50056;       // 50048
    int* blocksums = cursor + 50048;       // 256
    int* csr_src   = blocksums + 256;      // 600000

    size_t needed = ((size_t)(csr_src + EE) - (size_t)d_ws);
    if (ws_size < needed) return;   // workspace too small -> bail (will show as validation failure)

    // ---- zero accumulation buffers (every call: graph replays don't re-poison) ----
    hipMemsetAsync(s7, 0, ((size_t)NN * 8 + 50048) * sizeof(float), stream);   // s7 + degf
    hipMemsetAsync(counts, 0, 50048 * sizeof(int), stream);
    hipMemsetAsync(az + (size_t)NN * DD, 0, (size_t)(NPAD - NN) * DD * sizeof(float), stream); // pad rows

    // ---- one-time per call: projection + CSR build ----
    proj_x_kernel<<<(NN * DD) / 256, 256, 0, stream>>>(x, Wx, bx, h);
    edge_stats_kernel<<<(EE + 255) / 256, 256, 0, stream>>>(ea, ei, s7, degf, counts);
    count_scan1<<<SCAN_BLOCKS, 256, 0, stream>>>(counts, rowptr, blocksums);
    count_scan2<<<1, 256, 0, stream>>>(blocksums, rowptr);
    count_scan3<<<SCAN_BLOCKS, 256, 0, stream>>>(blocksums, rowptr, cursor);
    csr_fill_kernel<<<(EE + 255) / 256, 256, 0, stream>>>(ei, cursor, csr_src);

    // ---- layers ----
    for (int l = 0; l < LL; l++) {
        aggregate_kernel<<<NN / 4, 256, 0, stream>>>(h, rowptr, csr_src, s7, degf, We, be, az);
        gemm_kernel<<<dim3(NPAD / 64, HH / 64), 256, 0, stream>>>(
            az, W1 + (size_t)l * DD * HH, b1 + (size_t)l * HH, z1, DD, HH, 1);
        gemm_kernel<<<dim3(NPAD / 64, DD / 64), 256, 0, stream>>>(
            z1, W2 + (size_t)l * HH * DD, b2 + (size_t)l * DD, az, HH, DD, 0);
        hipMemsetAsync(sums, 0, 256 * sizeof(float), stream);
        bn_stats_kernel<<<256, 256, 0, stream>>>(az, sums);
        bn_finalize_kernel<<<1, 128, 0, stream>>>(sums, gamma + (size_t)l * DD,
                                                  beta + (size_t)l * DD, ab);
        float* outp = (l == LL - 1) ? (float*)d_out : h;
        bn_apply_kernel<<<(NN * DD) / 256, 256, 0, stream>>>(az, ab, outp, (l < LL - 1) ? 1 : 0);
    }
}

// Round 2
// 1113.556 us; speedup vs baseline: 1.4300x; 1.4300x over previous
//
#include <hip/hip_runtime.h>

#define NN   50000
#define NPAD 50048           // 391 * 128
#define EE   600000
#define DD   128
#define HH   256
#define LL   5
#define BN_EPS 1e-5f
#define SCAN_BLOCKS 196      // ceil(NN/256)

typedef _Float16 f16x8 __attribute__((ext_vector_type(8)));
typedef float    f32x4 __attribute__((ext_vector_type(4)));

// ---------------- input projection: h = x @ Wx + bx ----------------
__global__ void proj_x_kernel(const float* __restrict__ x, const float* __restrict__ Wx,
                              const float* __restrict__ bx, float* __restrict__ h)
{
    int idx = blockIdx.x * 256 + threadIdx.x;
    if (idx >= NN * DD) return;
    int n = idx >> 7, d = idx & 127;
    const float* xr = x + (size_t)n * 78;
    float acc = bx[d];
#pragma unroll
    for (int k = 0; k < 78; k++) acc = fmaf(xr[k], Wx[k * DD + d], acc);
    h[idx] = acc;
}

// ------------- edge counts (int atomics only) -------------
__global__ void count_kernel(const int* __restrict__ ei, int* __restrict__ counts)
{
    int e = blockIdx.x * 256 + threadIdx.x;
    if (e >= EE) return;
    atomicAdd(&counts[ei[EE + e]], 1);
}

// ---------------- 3-phase exclusive scan for CSR rowptr ----------------
__global__ void count_scan1(const int* __restrict__ counts, int* __restrict__ rowptr,
                            int* __restrict__ blocksums)
{
    __shared__ int buf[256];
    int i = blockIdx.x * 256 + threadIdx.x;
    int v = (i < NN) ? counts[i] : 0;
    int val = v;
    buf[threadIdx.x] = val;
    __syncthreads();
    for (int off = 1; off < 256; off <<= 1) {
        int t = (threadIdx.x >= off) ? buf[threadIdx.x - off] : 0;
        __syncthreads();
        val += t;
        buf[threadIdx.x] = val;
        __syncthreads();
    }
    if (i < NN) rowptr[i] = val - v;          // block-local exclusive
    if (threadIdx.x == 255) blocksums[blockIdx.x] = val;
}

__global__ void count_scan2(int* __restrict__ blocksums, int* __restrict__ rowptr)
{
    __shared__ int buf[256];
    int v = (threadIdx.x < SCAN_BLOCKS) ? blocksums[threadIdx.x] : 0;
    int val = v;
    buf[threadIdx.x] = val;
    __syncthreads();
    for (int off = 1; off < 256; off <<= 1) {
        int t = (threadIdx.x >= off) ? buf[threadIdx.x - off] : 0;
        __syncthreads();
        val += t;
        buf[threadIdx.x] = val;
        __syncthreads();
    }
    if (threadIdx.x < SCAN_BLOCKS) blocksums[threadIdx.x] = val - v;  // exclusive block offsets
    if (threadIdx.x == 255) rowptr[NN] = val;                         // total == EE
}

__global__ void count_scan3(const int* __restrict__ blocksums, int* __restrict__ rowptr,
                            int* __restrict__ cursor)
{
    int i = blockIdx.x * 256 + threadIdx.x;
    if (i < NN) {
        int r = rowptr[i] + blocksums[blockIdx.x];
        rowptr[i] = r;
        cursor[i] = r;
    }
}

__global__ void csr_fill_kernel(const int* __restrict__ ei, int* __restrict__ cursor,
                                int* __restrict__ csr_src, int* __restrict__ csr_eid)
{
    int e = blockIdx.x * 256 + threadIdx.x;
    if (e >= EE) return;
    int dst = ei[EE + e];
    int pos = atomicAdd(&cursor[dst], 1);
    csr_src[pos] = ei[e];
    csr_eid[pos] = e;
}

// -------- per-node edge-attr sums + degree (no atomics): s7[n][0..6], s7[n][7]=deg --------
__global__ __launch_bounds__(256) void node_prep_kernel(
    const float* __restrict__ ea, const int* __restrict__ rowptr,
    const int* __restrict__ csr_eid, float* __restrict__ s7)
{
    int n = blockIdx.x * 4 + (threadIdx.x >> 6);
    int lane = threadIdx.x & 63;
    if (n >= NN) return;
    int beg = rowptr[n], end = rowptr[n + 1];
    if (lane < 7) {
        float s = 0.f;
        for (int i = beg; i < end; i++)
            s += ea[(size_t)csr_eid[i] * 7 + lane];
        s7[n * 8 + lane] = s;
    } else if (lane == 7) {
        s7[n * 8 + 7] = (float)(end - beg);
    }
}

// -------- weight transpose+convert: W1T[l][n][k]=f16(W1[l][k][n]), W2T[l][n][k]=f16(W2[l][k][n]) --------
__global__ void conv_w_kernel(const float* __restrict__ W1, const float* __restrict__ W2,
                              _Float16* __restrict__ W1T, _Float16* __restrict__ W2T)
{
    int idx = blockIdx.x * 256 + threadIdx.x;
    if (idx >= LL * DD * HH) return;
    int l = idx / (DD * HH), r = idx % (DD * HH);
    int k1 = r / HH, n1 = r % HH;                       // W1 [l][k(128)][n(256)]
    W1T[(size_t)l * DD * HH + (size_t)n1 * DD + k1] = (_Float16)W1[idx];
    int k2 = r / DD, n2 = r % DD;                       // W2 [l][k(256)][n(128)]
    W2T[(size_t)l * DD * HH + (size_t)n2 * HH + k2] = (_Float16)W2[idx];
}

// --------- aggregation: agg[n] = sum_in h[src] + s7[n]@We + deg*be  -> f16 ---------
__global__ __launch_bounds__(256) void aggregate_kernel(
    const float* __restrict__ h, const int* __restrict__ rowptr,
    const int* __restrict__ csr_src, const float* __restrict__ s7,
    const float* __restrict__ We, const float* __restrict__ be,
    _Float16* __restrict__ aggH)
{
    __shared__ float sWe[7 * DD];
    for (int i = threadIdx.x; i < 7 * DD; i += 256) sWe[i] = We[i];
    __syncthreads();
    int n = blockIdx.x * 4 + (threadIdx.x >> 6);
    int lane = threadIdx.x & 63;
    if (n >= NN) return;
    int beg = rowptr[n], end = rowptr[n + 1];
    float a0 = 0.f, a1 = 0.f;
    for (int i = beg; i < end; i++) {
        const float* hr = h + (size_t)csr_src[i] * DD;
        a0 += hr[lane];
        a1 += hr[lane + 64];
    }
    float dg = s7[n * 8 + 7];
    float b0 = dg * be[lane], b1 = dg * be[lane + 64];
#pragma unroll
    for (int k = 0; k < 7; k++) {
        float sv = s7[n * 8 + k];
        b0 = fmaf(sv, sWe[k * DD + lane], b0);
        b1 = fmaf(sv, sWe[k * DD + lane + 64], b1);
    }
    aggH[(size_t)n * DD + lane]      = (_Float16)(a0 + b0);
    aggH[(size_t)n * DD + 64 + lane] = (_Float16)(a1 + b1);
}

// ---------------- f16 MFMA GEMM: C[M,Nn] = A[M,K] @ BT[Nn,K]^T + bias ----------------
// BM=128, BN=64, 4 waves (2x2), 64x32 per wave, direct global fragment loads (no LDS).
template<int K, int Nn>
__global__ __launch_bounds__(256) void gemm_f16(const _Float16* __restrict__ A,
    const _Float16* __restrict__ BT, const float* __restrict__ bias,
    void* __restrict__ Cout, int relu_f16out)
{
    const int tid = threadIdx.x;
    const int lane = tid & 63, wid = tid >> 6;
    const int wm = wid >> 1, wn = wid & 1;
    const int row0 = blockIdx.x * 128 + wm * 64;
    const int col0 = blockIdx.y * 64 + wn * 32;
    const int lr = lane & 15, lk = (lane >> 4) * 8;
    f32x4 acc[4][2] = {};
    const _Float16* Ap = A + (size_t)(row0 + lr) * K + lk;
    const _Float16* Bp = BT + (size_t)(col0 + lr) * K + lk;
#pragma unroll
    for (int ks = 0; ks < K; ks += 32) {
        f16x8 a[4], b[2];
#pragma unroll
        for (int f = 0; f < 4; f++) a[f] = *(const f16x8*)(Ap + (size_t)f * 16 * K + ks);
#pragma unroll
        for (int g = 0; g < 2; g++) b[g] = *(const f16x8*)(Bp + (size_t)g * 16 * K + ks);
#pragma unroll
        for (int f = 0; f < 4; f++)
#pragma unroll
            for (int g = 0; g < 2; g++)
                acc[f][g] = __builtin_amdgcn_mfma_f32_16x16x32_f16(a[f], b[g], acc[f][g], 0, 0, 0);
    }
#pragma unroll
    for (int f = 0; f < 4; f++) {
#pragma unroll
        for (int g = 0; g < 2; g++) {
            int col = col0 + g * 16 + lr;
            float bv = bias[col];
            int rbase = row0 + f * 16 + (lane >> 4) * 4;
#pragma unroll
            for (int j = 0; j < 4; j++) {
                float v = acc[f][g][j] + bv;
                if (relu_f16out) {
                    v = fmaxf(v, 0.f);
                    ((_Float16*)Cout)[(size_t)(rbase + j) * Nn + col] = (_Float16)v;
                } else {
                    ((float*)Cout)[(size_t)(rbase + j) * Nn + col] = v;
                }
            }
        }
    }
}

// ---------------- BatchNorm ----------------
__global__ void bn_stats_kernel(const float* __restrict__ z, float* __restrict__ sums)
{
    int gtid = blockIdx.x * 256 + threadIdx.x;    // 512 row streams x 128 dims
    int d = gtid & 127;
    float s = 0.f, s2 = 0.f;
    for (int n = gtid >> 7; n < NN; n += 512) {
        float v = z[(size_t)n * DD + d];
        s += v;
        s2 = fmaf(v, v, s2);
    }
    atomicAdd(&sums[d], s);
    atomicAdd(&sums[DD + d], s2);
}

__global__ void bn_finalize_kernel(const float* __restrict__ sums, const float* __restrict__ gamma,
                                   const float* __restrict__ beta, float* __restrict__ ab)
{
    int d = threadIdx.x;
    float mu  = sums[d] * (1.0f / NN);
    float var = sums[DD + d] * (1.0f / NN) - mu * mu;
    float inv = 1.0f / sqrtf(var + BN_EPS);
    float a = gamma[d] * inv;
    ab[d]      = a;
    ab[DD + d] = beta[d] - mu * a;
}

__global__ void bn_apply_kernel(const float* __restrict__ z, const float* __restrict__ ab,
                                float* __restrict__ out, int relu)
{
    int idx = blockIdx.x * 256 + threadIdx.x;
    if (idx >= NN * DD) return;
    int d = idx & 127;
    float v = fmaf(ab[d], z[idx], ab[DD + d]);
    if (relu) v = fmaxf(v, 0.f);
    out[idx] = v;
}

// ---------------------------------------------------------------------------
extern "C" void kernel_launch(void* const* d_in, const int* in_sizes, int n_in,
                              void* d_out, int out_size, void* d_ws, size_t ws_size,
                              hipStream_t stream)
{
    const float* x     = (const float*)d_in[0];
    const float* ea    = (const float*)d_in[1];
    const float* Wx    = (const float*)d_in[2];
    const float* bx    = (const float*)d_in[3];
    const float* We    = (const float*)d_in[4];
    const float* be    = (const float*)d_in[5];
    const float* W1    = (const float*)d_in[6];
    const float* b1    = (const float*)d_in[7];
    const float* W2    = (const float*)d_in[8];
    const float* b2    = (const float*)d_in[9];
    const float* gamma = (const float*)d_in[10];
    const float* beta  = (const float*)d_in[11];
    const int*   ei    = (const int*)d_in[12];

    // ---- workspace layout (byte offsets, 16B-aligned chunks) ----
    char* base = (char*)d_ws;
    size_t off = 0;
    auto alloc = [&](size_t bytes) { void* p = base + off; off += (bytes + 15) & ~(size_t)15; return p; };
    float*    h    = (float*)   alloc((size_t)NPAD * DD * 4);
    float*    az   = (float*)   alloc((size_t)NPAD * DD * 4);
    _Float16* aggH = (_Float16*)alloc((size_t)NPAD * DD * 2);
    _Float16* z1H  = (_Float16*)alloc((size_t)NPAD * HH * 2);
    float*    s7   = (float*)   alloc((size_t)NN * 8 * 4);
    _Float16* W1T  = (_Float16*)alloc((size_t)LL * DD * HH * 2);
    _Float16* W2T  = (_Float16*)alloc((size_t)LL * DD * HH * 2);
    float*    sums = (float*)   alloc(256 * 4);
    float*    ab   = (float*)   alloc(256 * 4);
    int* counts    = (int*)alloc(50048 * 4);
    int* rowptr    = (int*)alloc(50056 * 4);
    int* cursor    = (int*)alloc(50048 * 4);
    int* blocksums = (int*)alloc(256 * 4);
    int* csr_src   = (int*)alloc((size_t)EE * 4);
    int* csr_eid   = (int*)alloc((size_t)EE * 4);
    if (ws_size < off) return;   // workspace too small -> bail

    // ---- per-call zeroing (graph replays don't re-poison) ----
    hipMemsetAsync(counts, 0, 50048 * sizeof(int), stream);

    // ---- prolog: projection + CSR build + node prep + weight convert ----
    proj_x_kernel<<<(NN * DD) / 256, 256, 0, stream>>>(x, Wx, bx, h);
    count_kernel<<<(EE + 255) / 256, 256, 0, stream>>>(ei, counts);
    count_scan1<<<SCAN_BLOCKS, 256, 0, stream>>>(counts, rowptr, blocksums);
    count_scan2<<<1, 256, 0, stream>>>(blocksums, rowptr);
    count_scan3<<<SCAN_BLOCKS, 256, 0, stream>>>(blocksums, rowptr, cursor);
    csr_fill_kernel<<<(EE + 255) / 256, 256, 0, stream>>>(ei, cursor, csr_src, csr_eid);
    node_prep_kernel<<<(NN + 3) / 4, 256, 0, stream>>>(ea, rowptr, csr_eid, s7);
    conv_w_kernel<<<(LL * DD * HH + 255) / 256, 256, 0, stream>>>(W1, W2, W1T, W2T);

    // ---- layers ----
    for (int l = 0; l < LL; l++) {
        aggregate_kernel<<<(NN + 3) / 4, 256, 0, stream>>>(h, rowptr, csr_src, s7, We, be, aggH);
        gemm_f16<DD, HH><<<dim3(NPAD / 128, HH / 64), 256, 0, stream>>>(
            aggH, W1T + (size_t)l * DD * HH, b1 + (size_t)l * HH, z1H, 1);
        gemm_f16<HH, DD><<<dim3(NPAD / 128, DD / 64), 256, 0, stream>>>(
            z1H, W2T + (size_t)l * DD * HH, b2 + (size_t)l * DD, az, 0);
        hipMemsetAsync(sums, 0, 256 * sizeof(float), stream);
        bn_stats_kernel<<<256, 256, 0, stream>>>(az, sums);
        bn_finalize_kernel<<<1, 128, 0, stream>>>(sums, gamma + (size_t)l * DD,
                                                  beta + (size_t)l * DD, ab);
        float* outp = (l == LL - 1) ? (float*)d_out : h;
        bn_apply_kernel<<<(NN * DD) / 256, 256, 0, stream>>>(az, ab, outp, (l < LL - 1) ? 1 : 0);
    }
}

// Round 3
// 813.287 us; speedup vs baseline: 1.9580x; 1.3692x over previous
//
#include <hip/hip_runtime.h>

#define NN   50000
#define NPAD 50048           // 391 * 128
#define EE   600000
#define DD   128
#define HH   256
#define KX   96              // padded K for x-projection (78 -> 96)
#define LL   5
#define BN_EPS 1e-5f
#define SCAN_BLOCKS 196      // ceil(NN/256)

typedef _Float16 f16x8 __attribute__((ext_vector_type(8)));
typedef float    f32x4 __attribute__((ext_vector_type(4)));

union U32F16 { unsigned int u; _Float16 h[2]; };

// ---------------- convert x -> f16 padded [NPAD][96] ----------------
__global__ void conv_x_kernel(const float* __restrict__ x, _Float16* __restrict__ xH)
{
    int idx = blockIdx.x * 256 + threadIdx.x;
    if (idx >= NPAD * KX) return;
    int n = idx / KX, k = idx % KX;
    float v = (n < NN && k < 78) ? x[(size_t)n * 78 + k] : 0.f;
    xH[idx] = (_Float16)v;
}

// ---------------- convert weights: WxT[d][k], W1T[l][n][k], W2T[l][n][k] ----------------
__global__ void conv_wx_kernel(const float* __restrict__ Wx, _Float16* __restrict__ WxT)
{
    int idx = blockIdx.x * 256 + threadIdx.x;
    if (idx >= DD * KX) return;
    int d = idx / KX, k = idx % KX;
    WxT[idx] = (_Float16)((k < 78) ? Wx[(size_t)k * DD + d] : 0.f);
}

__global__ void conv_w_kernel(const float* __restrict__ W1, const float* __restrict__ W2,
                              _Float16* __restrict__ W1T, _Float16* __restrict__ W2T)
{
    int idx = blockIdx.x * 256 + threadIdx.x;
    if (idx >= LL * DD * HH) return;
    int l = idx / (DD * HH), r = idx % (DD * HH);
    int k1 = r / HH, n1 = r % HH;                       // W1 [l][k(128)][n(256)]
    W1T[(size_t)l * DD * HH + (size_t)n1 * DD + k1] = (_Float16)W1[idx];
    int k2 = r / DD, n2 = r % DD;                       // W2 [l][k(256)][n(128)]
    W2T[(size_t)l * DD * HH + (size_t)n2 * HH + k2] = (_Float16)W2[idx];
}

// ------------- edge counts (int atomics only) -------------
__global__ void count_kernel(const int* __restrict__ ei, int* __restrict__ counts)
{
    int e = blockIdx.x * 256 + threadIdx.x;
    if (e >= EE) return;
    atomicAdd(&counts[ei[EE + e]], 1);
}

// ---------------- 3-phase exclusive scan for CSR rowptr ----------------
__global__ void count_scan1(const int* __restrict__ counts, int* __restrict__ rowptr,
                            int* __restrict__ blocksums)
{
    __shared__ int buf[256];
    int i = blockIdx.x * 256 + threadIdx.x;
    int v = (i < NN) ? counts[i] : 0;
    int val = v;
    buf[threadIdx.x] = val;
    __syncthreads();
    for (int off = 1; off < 256; off <<= 1) {
        int t = (threadIdx.x >= off) ? buf[threadIdx.x - off] : 0;
        __syncthreads();
        val += t;
        buf[threadIdx.x] = val;
        __syncthreads();
    }
    if (i < NN) rowptr[i] = val - v;
    if (threadIdx.x == 255) blocksums[blockIdx.x] = val;
}

__global__ void count_scan2(int* __restrict__ blocksums, int* __restrict__ rowptr)
{
    __shared__ int buf[256];
    int v = (threadIdx.x < SCAN_BLOCKS) ? blocksums[threadIdx.x] : 0;
    int val = v;
    buf[threadIdx.x] = val;
    __syncthreads();
    for (int off = 1; off < 256; off <<= 1) {
        int t = (threadIdx.x >= off) ? buf[threadIdx.x - off] : 0;
        __syncthreads();
        val += t;
        buf[threadIdx.x] = val;
        __syncthreads();
    }
    if (threadIdx.x < SCAN_BLOCKS) blocksums[threadIdx.x] = val - v;
    if (threadIdx.x == 255) rowptr[NN] = val;
}

__global__ void count_scan3(const int* __restrict__ blocksums, int* __restrict__ rowptr,
                            int* __restrict__ cursor)
{
    int i = blockIdx.x * 256 + threadIdx.x;
    if (i < NN) {
        int r = rowptr[i] + blocksums[blockIdx.x];
        rowptr[i] = r;
        cursor[i] = r;
    }
}

__global__ void csr_fill_kernel(const int* __restrict__ ei, int* __restrict__ cursor,
                                int* __restrict__ csr_src, int* __restrict__ csr_eid)
{
    int e = blockIdx.x * 256 + threadIdx.x;
    if (e >= EE) return;
    int dst = ei[EE + e];
    int pos = atomicAdd(&cursor[dst], 1);
    csr_src[pos] = ei[e];
    csr_eid[pos] = e;
}

// -------- per-node edge-attr sums + degree: s7[n][0..6], s7[n][7]=deg --------
// lane = 8*j + k : 8 edges x 7 attrs per iteration, shfl_xor reduce over j.
__global__ __launch_bounds__(256) void node_prep_kernel(
    const float* __restrict__ ea, const int* __restrict__ rowptr,
    const int* __restrict__ csr_eid, float* __restrict__ s7)
{
    int n = blockIdx.x * 4 + (threadIdx.x >> 6);
    int lane = threadIdx.x & 63;
    if (n >= NN) return;
    int beg = rowptr[n], end = rowptr[n + 1];
    int j = lane >> 3, k = lane & 7;
    float s = 0.f;
    if (k < 7) {
        for (int base = beg; base < end; base += 8) {
            int e_i = base + j;
            if (e_i < end) s += ea[(size_t)csr_eid[e_i] * 7 + k];
        }
    }
    s += __shfl_xor(s, 8);
    s += __shfl_xor(s, 16);
    s += __shfl_xor(s, 32);
    if (lane < 7)      s7[n * 8 + lane] = s;
    else if (lane == 7) s7[n * 8 + 7] = (float)(end - beg);
}

// --------- aggregation: agg[n] = sum_in h[src] + s7[n]@We + deg*be  -> f16 ---------
__global__ __launch_bounds__(256) void aggregate_kernel(
    const _Float16* __restrict__ h, const int* __restrict__ rowptr,
    const int* __restrict__ csr_src, const float* __restrict__ s7,
    const float* __restrict__ We, const float* __restrict__ be,
    _Float16* __restrict__ aggH)
{
    __shared__ float sWe[7 * DD];
    for (int i = threadIdx.x; i < 7 * DD; i += 256) sWe[i] = We[i];
    __syncthreads();
    int n = blockIdx.x * 4 + (threadIdx.x >> 6);
    int lane = threadIdx.x & 63;
    if (n >= NN) return;
    const unsigned int* h32 = (const unsigned int*)h;
    int beg = rowptr[n], end = rowptr[n + 1];
    float a0 = 0.f, a1 = 0.f;
    for (int i = beg; i < end; i++) {
        U32F16 u; u.u = h32[(size_t)csr_src[i] * 64 + lane];
        a0 += (float)u.h[0];
        a1 += (float)u.h[1];
    }
    int d0 = 2 * lane, d1 = 2 * lane + 1;
    float dg = s7[n * 8 + 7];
    float b0 = dg * be[d0], b1 = dg * be[d1];
#pragma unroll
    for (int k = 0; k < 7; k++) {
        float sv = s7[n * 8 + k];
        b0 = fmaf(sv, sWe[k * DD + d0], b0);
        b1 = fmaf(sv, sWe[k * DD + d1], b1);
    }
    U32F16 o; o.h[0] = (_Float16)(a0 + b0); o.h[1] = (_Float16)(a1 + b1);
    ((unsigned int*)aggH)[(size_t)n * 64 + lane] = o.u;
}

// ---------------- f16 MFMA GEMM: C[M,Nn] = A[M,K] @ BT[Nn,K]^T + bias ----------------
// BM=128, BN=64, 4 waves (2x2), 64x32 per wave, direct global fragment loads.
// STATS: accumulate per-column sum/sumsq (rows < NN) into sums[0:Nn]/sums[Nn..]
template<int K, int Nn, int RELU, int STATS>
__global__ __launch_bounds__(256) void gemm_f16(const _Float16* __restrict__ A,
    const _Float16* __restrict__ BT, const float* __restrict__ bias,
    _Float16* __restrict__ C, float* __restrict__ sums)
{
    const int tid = threadIdx.x;
    const int lane = tid & 63, wid = tid >> 6;
    const int wm = wid >> 1, wn = wid & 1;
    const int row0 = blockIdx.x * 128 + wm * 64;
    const int col0 = blockIdx.y * 64 + wn * 32;
    const int lr = lane & 15, lk = (lane >> 4) * 8;
    f32x4 acc[4][2] = {};
    const _Float16* Ap = A + (size_t)(row0 + lr) * K + lk;
    const _Float16* Bp = BT + (size_t)(col0 + lr) * K + lk;
#pragma unroll
    for (int ks = 0; ks < K; ks += 32) {
        f16x8 a[4], b[2];
#pragma unroll
        for (int f = 0; f < 4; f++) a[f] = *(const f16x8*)(Ap + (size_t)f * 16 * K + ks);
#pragma unroll
        for (int g = 0; g < 2; g++) b[g] = *(const f16x8*)(Bp + (size_t)g * 16 * K + ks);
#pragma unroll
        for (int f = 0; f < 4; f++)
#pragma unroll
            for (int g = 0; g < 2; g++)
                acc[f][g] = __builtin_amdgcn_mfma_f32_16x16x32_f16(a[f], b[g], acc[f][g], 0, 0, 0);
    }
    float sp[2] = {0.f, 0.f}, sp2[2] = {0.f, 0.f};
#pragma unroll
    for (int f = 0; f < 4; f++) {
#pragma unroll
        for (int g = 0; g < 2; g++) {
            int col = col0 + g * 16 + lr;
            float bv = bias[col];
            int rbase = row0 + f * 16 + (lane >> 4) * 4;
#pragma unroll
            for (int j = 0; j < 4; j++) {
                float v = acc[f][g][j] + bv;
                if (RELU) v = fmaxf(v, 0.f);
                C[(size_t)(rbase + j) * Nn + col] = (_Float16)v;
                if (STATS) {
                    float keep = (rbase + j < NN) ? 1.f : 0.f;
                    sp[g]  = fmaf(v, keep, sp[g]);
                    sp2[g] = fmaf(v * v, keep, sp2[g]);
                }
            }
        }
    }
    if (STATS) {
        __shared__ float red[2][2][32];
#pragma unroll
        for (int g = 0; g < 2; g++) {
            sp[g]  += __shfl_xor(sp[g], 16);  sp[g]  += __shfl_xor(sp[g], 32);
            sp2[g] += __shfl_xor(sp2[g], 16); sp2[g] += __shfl_xor(sp2[g], 32);
        }
        if (wm == 0 && lane < 16) {
#pragma unroll
            for (int g = 0; g < 2; g++) {
                red[wn][0][g * 16 + lr] = sp[g];
                red[wn][1][g * 16 + lr] = sp2[g];
            }
        }
        __syncthreads();
        if (wm == 1 && lane < 16) {
#pragma unroll
            for (int g = 0; g < 2; g++) {
                int col = col0 + g * 16 + lr;
                atomicAdd(&sums[col],      sp[g]  + red[wn][0][g * 16 + lr]);
                atomicAdd(&sums[Nn + col], sp2[g] + red[wn][1][g * 16 + lr]);
            }
        }
    }
}

// ---------------- BN apply (finalize inlined) ----------------
__global__ void bn_apply_kernel(const _Float16* __restrict__ z, const float* __restrict__ sums,
                                const float* __restrict__ gamma, const float* __restrict__ beta,
                                float* __restrict__ outF, _Float16* __restrict__ outH, int last)
{
    int idx = blockIdx.x * 256 + threadIdx.x;   // over NN*64 u32 pairs
    if (idx >= NN * 64) return;
    int li = idx & 63;
    int d0 = 2 * li, d1 = d0 + 1;
    const float invN = 1.0f / NN;
    float mu0 = sums[d0] * invN, mu1 = sums[d1] * invN;
    float var0 = fmaf(-mu0, mu0, sums[DD + d0] * invN);
    float var1 = fmaf(-mu1, mu1, sums[DD + d1] * invN);
    float i0 = rsqrtf(var0 + BN_EPS), i1 = rsqrtf(var1 + BN_EPS);
    float a0 = gamma[d0] * i0, a1 = gamma[d1] * i1;
    float c0 = fmaf(-mu0, a0, beta[d0]), c1 = fmaf(-mu1, a1, beta[d1]);
    U32F16 u; u.u = ((const unsigned int*)z)[idx];
    float v0 = fmaf(a0, (float)u.h[0], c0);
    float v1 = fmaf(a1, (float)u.h[1], c1);
    if (last) {
        int n = idx >> 6;
        float2 o = make_float2(v0, v1);
        *(float2*)(outF + (size_t)n * DD + d0) = o;
    } else {
        U32F16 o;
        o.h[0] = (_Float16)fmaxf(v0, 0.f);
        o.h[1] = (_Float16)fmaxf(v1, 0.f);
        ((unsigned int*)outH)[idx] = o.u;
    }
}

// ---------------------------------------------------------------------------
extern "C" void kernel_launch(void* const* d_in, const int* in_sizes, int n_in,
                              void* d_out, int out_size, void* d_ws, size_t ws_size,
                              hipStream_t stream)
{
    const float* x     = (const float*)d_in[0];
    const float* ea    = (const float*)d_in[1];
    const float* Wx    = (const float*)d_in[2];
    const float* bx    = (const float*)d_in[3];
    const float* We    = (const float*)d_in[4];
    const float* be    = (const float*)d_in[5];
    const float* W1    = (const float*)d_in[6];
    const float* b1    = (const float*)d_in[7];
    const float* W2    = (const float*)d_in[8];
    const float* b2    = (const float*)d_in[9];
    const float* gamma = (const float*)d_in[10];
    const float* beta  = (const float*)d_in[11];
    const int*   ei    = (const int*)d_in[12];

    // ---- workspace layout ----
    char* base = (char*)d_ws;
    size_t off = 0;
    auto alloc = [&](size_t bytes) { void* p = base + off; off += (bytes + 15) & ~(size_t)15; return p; };
    _Float16* h16  = (_Float16*)alloc((size_t)NPAD * DD * 2);
    _Float16* aggH = (_Float16*)alloc((size_t)NPAD * DD * 2);
    _Float16* z1H  = (_Float16*)alloc((size_t)NPAD * HH * 2);
    _Float16* az16 = (_Float16*)alloc((size_t)NPAD * DD * 2);
    _Float16* xH   = (_Float16*)alloc((size_t)NPAD * KX * 2);
    _Float16* WxT  = (_Float16*)alloc((size_t)DD * KX * 2);
    _Float16* W1T  = (_Float16*)alloc((size_t)LL * DD * HH * 2);
    _Float16* W2T  = (_Float16*)alloc((size_t)LL * DD * HH * 2);
    float*    s7   = (float*)   alloc((size_t)NN * 8 * 4);
    float*    sums = (float*)   alloc(256 * 4);
    int* counts    = (int*)alloc(50048 * 4);
    int* rowptr    = (int*)alloc(50056 * 4);
    int* cursor    = (int*)alloc(50048 * 4);
    int* blocksums = (int*)alloc(256 * 4);
    int* csr_src   = (int*)alloc((size_t)EE * 4);
    int* csr_eid   = (int*)alloc((size_t)EE * 4);
    if (ws_size < off) return;

    // ---- per-call zeroing ----
    hipMemsetAsync(counts, 0, 50048 * sizeof(int), stream);
    hipMemsetAsync(aggH + (size_t)NN * DD, 0, (size_t)(NPAD - NN) * DD * 2, stream); // pad rows

    // ---- prolog ----
    conv_x_kernel<<<(NPAD * KX + 255) / 256, 256, 0, stream>>>(x, xH);
    conv_wx_kernel<<<(DD * KX + 255) / 256, 256, 0, stream>>>(Wx, WxT);
    conv_w_kernel<<<(LL * DD * HH + 255) / 256, 256, 0, stream>>>(W1, W2, W1T, W2T);
    gemm_f16<KX, DD, 0, 0><<<dim3(NPAD / 128, DD / 64), 256, 0, stream>>>(
        xH, WxT, bx, h16, nullptr);
    count_kernel<<<(EE + 255) / 256, 256, 0, stream>>>(ei, counts);
    count_scan1<<<SCAN_BLOCKS, 256, 0, stream>>>(counts, rowptr, blocksums);
    count_scan2<<<1, 256, 0, stream>>>(blocksums, rowptr);
    count_scan3<<<SCAN_BLOCKS, 256, 0, stream>>>(blocksums, rowptr, cursor);
    csr_fill_kernel<<<(EE + 255) / 256, 256, 0, stream>>>(ei, cursor, csr_src, csr_eid);
    node_prep_kernel<<<(NN + 3) / 4, 256, 0, stream>>>(ea, rowptr, csr_eid, s7);

    // ---- layers ----
    for (int l = 0; l < LL; l++) {
        aggregate_kernel<<<(NN + 3) / 4, 256, 0, stream>>>(h16, rowptr, csr_src, s7, We, be, aggH);
        gemm_f16<DD, HH, 1, 0><<<dim3(NPAD / 128, HH / 64), 256, 0, stream>>>(
            aggH, W1T + (size_t)l * DD * HH, b1 + (size_t)l * HH, z1H, nullptr);
        hipMemsetAsync(sums, 0, 256 * sizeof(float), stream);
        gemm_f16<HH, DD, 0, 1><<<dim3(NPAD / 128, DD / 64), 256, 0, stream>>>(
            z1H, W2T + (size_t)l * DD * HH, b2 + (size_t)l * DD, az16, sums);
        bn_apply_kernel<<<(NN * 64 + 255) / 256, 256, 0, stream>>>(
            az16, sums, gamma + (size_t)l * DD, beta + (size_t)l * DD,
            (float*)d_out, h16, (l == LL - 1) ? 1 : 0);
    }
}

// Round 4
// 627.341 us; speedup vs baseline: 2.5384x; 1.2964x over previous
//
#include <hip/hip_runtime.h>

#define NN   50000
#define NPAD 50048           // 391 * 128
#define EE   600000
#define DD   128
#define HH   256
#define KX   96              // padded K for x-projection (78 -> 96)
#define LL   5
#define BN_EPS 1e-5f
#define SCAN_BLOCKS 196      // ceil(NN/256)

typedef _Float16 f16x8 __attribute__((ext_vector_type(8)));
typedef float    f32x4 __attribute__((ext_vector_type(4)));

union U32F16 { unsigned int u; _Float16 h[2]; };

// ---------------- convert x -> f16 padded [NPAD][96] ----------------
__global__ void conv_x_kernel(const float* __restrict__ x, _Float16* __restrict__ xH)
{
    int idx = blockIdx.x * 256 + threadIdx.x;
    if (idx >= NPAD * KX) return;
    int n = idx / KX, k = idx % KX;
    float v = (n < NN && k < 78) ? x[(size_t)n * 78 + k] : 0.f;
    xH[idx] = (_Float16)v;
}

// ---------------- convert weights: WxT[d][k], W1T[l][n][k], W2T[l][n][k] ----------------
__global__ void conv_wx_kernel(const float* __restrict__ Wx, _Float16* __restrict__ WxT)
{
    int idx = blockIdx.x * 256 + threadIdx.x;
    if (idx >= DD * KX) return;
    int d = idx / KX, k = idx % KX;
    WxT[idx] = (_Float16)((k < 78) ? Wx[(size_t)k * DD + d] : 0.f);
}

__global__ void conv_w_kernel(const float* __restrict__ W1, const float* __restrict__ W2,
                              _Float16* __restrict__ W1T, _Float16* __restrict__ W2T)
{
    int idx = blockIdx.x * 256 + threadIdx.x;
    if (idx >= LL * DD * HH) return;
    int l = idx / (DD * HH), r = idx % (DD * HH);
    int k1 = r / HH, n1 = r % HH;                       // W1 [l][k(128)][n(256)]
    W1T[(size_t)l * DD * HH + (size_t)n1 * DD + k1] = (_Float16)W1[idx];
    int k2 = r / DD, n2 = r % DD;                       // W2 [l][k(256)][n(128)]
    W2T[(size_t)l * DD * HH + (size_t)n2 * HH + k2] = (_Float16)W2[idx];
}

// ------------- edge counts (int atomics only) -------------
__global__ void count_kernel(const int* __restrict__ ei, int* __restrict__ counts)
{
    int e = blockIdx.x * 256 + threadIdx.x;
    if (e >= EE) return;
    atomicAdd(&counts[ei[EE + e]], 1);
}

// ---------------- 3-phase exclusive scan for CSR rowptr ----------------
__global__ void count_scan1(const int* __restrict__ counts, int* __restrict__ rowptr,
                            int* __restrict__ blocksums)
{
    __shared__ int buf[256];
    int i = blockIdx.x * 256 + threadIdx.x;
    int v = (i < NN) ? counts[i] : 0;
    int val = v;
    buf[threadIdx.x] = val;
    __syncthreads();
    for (int off = 1; off < 256; off <<= 1) {
        int t = (threadIdx.x >= off) ? buf[threadIdx.x - off] : 0;
        __syncthreads();
        val += t;
        buf[threadIdx.x] = val;
        __syncthreads();
    }
    if (i < NN) rowptr[i] = val - v;
    if (threadIdx.x == 255) blocksums[blockIdx.x] = val;
}

__global__ void count_scan2(int* __restrict__ blocksums, int* __restrict__ rowptr)
{
    __shared__ int buf[256];
    int v = (threadIdx.x < SCAN_BLOCKS) ? blocksums[threadIdx.x] : 0;
    int val = v;
    buf[threadIdx.x] = val;
    __syncthreads();
    for (int off = 1; off < 256; off <<= 1) {
        int t = (threadIdx.x >= off) ? buf[threadIdx.x - off] : 0;
        __syncthreads();
        val += t;
        buf[threadIdx.x] = val;
        __syncthreads();
    }
    if (threadIdx.x < SCAN_BLOCKS) blocksums[threadIdx.x] = val - v;
    if (threadIdx.x == 255) rowptr[NN] = val;
}

__global__ void count_scan3(const int* __restrict__ blocksums, int* __restrict__ rowptr,
                            int* __restrict__ cursor)
{
    int i = blockIdx.x * 256 + threadIdx.x;
    if (i < NN) {
        int r = rowptr[i] + blocksums[blockIdx.x];
        rowptr[i] = r;
        cursor[i] = r;
    }
}

__global__ void csr_fill_kernel(const int* __restrict__ ei, int* __restrict__ cursor,
                                int* __restrict__ csr_src, int* __restrict__ csr_eid)
{
    int e = blockIdx.x * 256 + threadIdx.x;
    if (e >= EE) return;
    int dst = ei[EE + e];
    int pos = atomicAdd(&cursor[dst], 1);
    csr_src[pos] = ei[e];
    csr_eid[pos] = e;
}

// -------- per-node edge-attr sums + degree: s7[n][0..6], s7[n][7]=deg --------
__global__ __launch_bounds__(256) void node_prep_kernel(
    const float* __restrict__ ea, const int* __restrict__ rowptr,
    const int* __restrict__ csr_eid, float* __restrict__ s7)
{
    int n = blockIdx.x * 4 + (threadIdx.x >> 6);
    int lane = threadIdx.x & 63;
    if (n >= NN) return;
    int beg = rowptr[n], end = rowptr[n + 1];
    int j = lane >> 3, k = lane & 7;
    float s = 0.f;
    if (k < 7) {
        for (int base = beg; base < end; base += 8) {
            int e_i = base + j;
            if (e_i < end) s += ea[(size_t)csr_eid[e_i] * 7 + k];
        }
    }
    s += __shfl_xor(s, 8);
    s += __shfl_xor(s, 16);
    s += __shfl_xor(s, 32);
    if (lane < 7)      s7[n * 8 + lane] = s;
    else if (lane == 7) s7[n * 8 + 7] = (float)(end - beg);
}

// --------- aggregation with fused BN(l-1)+ReLU on gathered rows ---------
// agg[n] = sum_{src in-edges} act(z[src]) + s7[n]@We + deg*be   -> f16
// act(v) = APPLYBN ? relu(a*v+c) : v   (a,c from sums/gamma/beta of prev layer)
template<int APPLYBN>
__global__ __launch_bounds__(256) void aggregate_kernel(
    const _Float16* __restrict__ zin, const int* __restrict__ rowptr,
    const int* __restrict__ csr_src, const float* __restrict__ s7,
    const float* __restrict__ We, const float* __restrict__ be,
    const float* __restrict__ sums, const float* __restrict__ gamma,
    const float* __restrict__ beta, _Float16* __restrict__ aggH)
{
    __shared__ float sWe[7 * DD];
    for (int i = threadIdx.x; i < 7 * DD; i += 256) sWe[i] = We[i];
    __syncthreads();
    int n = blockIdx.x * 4 + (threadIdx.x >> 6);
    int lane = threadIdx.x & 63;
    if (n >= NN) return;
    int d0 = 2 * lane, d1 = d0 + 1;
    float A0 = 1.f, C0 = 0.f, A1 = 1.f, C1 = 0.f;
    if (APPLYBN) {
        const float invN = 1.0f / NN;
        float mu0 = sums[d0] * invN, mu1 = sums[d1] * invN;
        float v0 = fmaf(-mu0, mu0, sums[DD + d0] * invN);
        float v1 = fmaf(-mu1, mu1, sums[DD + d1] * invN);
        A0 = gamma[d0] * rsqrtf(v0 + BN_EPS);
        A1 = gamma[d1] * rsqrtf(v1 + BN_EPS);
        C0 = fmaf(-mu0, A0, beta[d0]);
        C1 = fmaf(-mu1, A1, beta[d1]);
    }
    const unsigned int* z32 = (const unsigned int*)zin;
    int beg = rowptr[n], end = rowptr[n + 1];
    float a0 = 0.f, a1 = 0.f;
    int i = beg;
#define ACT0(uu) (APPLYBN ? fmaxf(fmaf(A0, (float)(uu).h[0], C0), 0.f) : (float)(uu).h[0])
#define ACT1(uu) (APPLYBN ? fmaxf(fmaf(A1, (float)(uu).h[1], C1), 0.f) : (float)(uu).h[1])
    for (; i + 4 <= end; i += 4) {
        int s0 = csr_src[i], s1 = csr_src[i + 1], s2 = csr_src[i + 2], s3 = csr_src[i + 3];
        U32F16 u0, u1, u2, u3;
        u0.u = z32[(size_t)s0 * 64 + lane];
        u1.u = z32[(size_t)s1 * 64 + lane];
        u2.u = z32[(size_t)s2 * 64 + lane];
        u3.u = z32[(size_t)s3 * 64 + lane];
        a0 += (ACT0(u0) + ACT0(u1)) + (ACT0(u2) + ACT0(u3));
        a1 += (ACT1(u0) + ACT1(u1)) + (ACT1(u2) + ACT1(u3));
    }
    for (; i < end; i++) {
        U32F16 u; u.u = z32[(size_t)csr_src[i] * 64 + lane];
        a0 += ACT0(u);
        a1 += ACT1(u);
    }
#undef ACT0
#undef ACT1
    float dg = s7[n * 8 + 7];
    float b0 = dg * be[d0], b1 = dg * be[d1];
#pragma unroll
    for (int k = 0; k < 7; k++) {
        float sv = s7[n * 8 + k];
        b0 = fmaf(sv, sWe[k * DD + d0], b0);
        b1 = fmaf(sv, sWe[k * DD + d1], b1);
    }
    U32F16 o; o.h[0] = (_Float16)(a0 + b0); o.h[1] = (_Float16)(a1 + b1);
    ((unsigned int*)aggH)[(size_t)n * 64 + lane] = o.u;
}

// ---------------- f16 MFMA GEMM: C[M,Nn] = A[M,K] @ BT[Nn,K]^T + bias ----------------
template<int K, int Nn, int RELU, int STATS>
__global__ __launch_bounds__(256) void gemm_f16(const _Float16* __restrict__ A,
    const _Float16* __restrict__ BT, const float* __restrict__ bias,
    _Float16* __restrict__ C, float* __restrict__ sums)
{
    const int tid = threadIdx.x;
    const int lane = tid & 63, wid = tid >> 6;
    const int wm = wid >> 1, wn = wid & 1;
    const int row0 = blockIdx.x * 128 + wm * 64;
    const int col0 = blockIdx.y * 64 + wn * 32;
    const int lr = lane & 15, lk = (lane >> 4) * 8;
    f32x4 acc[4][2] = {};
    const _Float16* Ap = A + (size_t)(row0 + lr) * K + lk;
    const _Float16* Bp = BT + (size_t)(col0 + lr) * K + lk;
#pragma unroll
    for (int ks = 0; ks < K; ks += 32) {
        f16x8 a[4], b[2];
#pragma unroll
        for (int f = 0; f < 4; f++) a[f] = *(const f16x8*)(Ap + (size_t)f * 16 * K + ks);
#pragma unroll
        for (int g = 0; g < 2; g++) b[g] = *(const f16x8*)(Bp + (size_t)g * 16 * K + ks);
#pragma unroll
        for (int f = 0; f < 4; f++)
#pragma unroll
            for (int g = 0; g < 2; g++)
                acc[f][g] = __builtin_amdgcn_mfma_f32_16x16x32_f16(a[f], b[g], acc[f][g], 0, 0, 0);
    }
    float sp[2] = {0.f, 0.f}, sp2[2] = {0.f, 0.f};
#pragma unroll
    for (int f = 0; f < 4; f++) {
#pragma unroll
        for (int g = 0; g < 2; g++) {
            int col = col0 + g * 16 + lr;
            float bv = bias[col];
            int rbase = row0 + f * 16 + (lane >> 4) * 4;
#pragma unroll
            for (int j = 0; j < 4; j++) {
                float v = acc[f][g][j] + bv;
                if (RELU) v = fmaxf(v, 0.f);
                C[(size_t)(rbase + j) * Nn + col] = (_Float16)v;
                if (STATS) {
                    float keep = (rbase + j < NN) ? 1.f : 0.f;
                    sp[g]  = fmaf(v, keep, sp[g]);
                    sp2[g] = fmaf(v * v, keep, sp2[g]);
                }
            }
        }
    }
    if (STATS) {
        __shared__ float red[2][2][32];
#pragma unroll
        for (int g = 0; g < 2; g++) {
            sp[g]  += __shfl_xor(sp[g], 16);  sp[g]  += __shfl_xor(sp[g], 32);
            sp2[g] += __shfl_xor(sp2[g], 16); sp2[g] += __shfl_xor(sp2[g], 32);
        }
        if (wm == 0 && lane < 16) {
#pragma unroll
            for (int g = 0; g < 2; g++) {
                red[wn][0][g * 16 + lr] = sp[g];
                red[wn][1][g * 16 + lr] = sp2[g];
            }
        }
        __syncthreads();
        if (wm == 1 && lane < 16) {
#pragma unroll
            for (int g = 0; g < 2; g++) {
                int col = col0 + g * 16 + lr;
                atomicAdd(&sums[col],      sp[g]  + red[wn][0][g * 16 + lr]);
                atomicAdd(&sums[Nn + col], sp2[g] + red[wn][1][g * 16 + lr]);
            }
        }
    }
}

// ---------------- final BN apply -> f32 d_out ----------------
__global__ void bn_apply_kernel(const _Float16* __restrict__ z, const float* __restrict__ sums,
                                const float* __restrict__ gamma, const float* __restrict__ beta,
                                float* __restrict__ outF)
{
    int idx = blockIdx.x * 256 + threadIdx.x;   // over NN*64 u32 pairs
    if (idx >= NN * 64) return;
    int li = idx & 63;
    int d0 = 2 * li, d1 = d0 + 1;
    const float invN = 1.0f / NN;
    float mu0 = sums[d0] * invN, mu1 = sums[d1] * invN;
    float var0 = fmaf(-mu0, mu0, sums[DD + d0] * invN);
    float var1 = fmaf(-mu1, mu1, sums[DD + d1] * invN);
    float i0 = rsqrtf(var0 + BN_EPS), i1 = rsqrtf(var1 + BN_EPS);
    float a0 = gamma[d0] * i0, a1 = gamma[d1] * i1;
    float c0 = fmaf(-mu0, a0, beta[d0]), c1 = fmaf(-mu1, a1, beta[d1]);
    U32F16 u; u.u = ((const unsigned int*)z)[idx];
    int n = idx >> 6;
    float2 o = make_float2(fmaf(a0, (float)u.h[0], c0), fmaf(a1, (float)u.h[1], c1));
    *(float2*)(outF + (size_t)n * DD + d0) = o;
}

// ---------------------------------------------------------------------------
extern "C" void kernel_launch(void* const* d_in, const int* in_sizes, int n_in,
                              void* d_out, int out_size, void* d_ws, size_t ws_size,
                              hipStream_t stream)
{
    const float* x     = (const float*)d_in[0];
    const float* ea    = (const float*)d_in[1];
    const float* Wx    = (const float*)d_in[2];
    const float* bx    = (const float*)d_in[3];
    const float* We    = (const float*)d_in[4];
    const float* be    = (const float*)d_in[5];
    const float* W1    = (const float*)d_in[6];
    const float* b1    = (const float*)d_in[7];
    const float* W2    = (const float*)d_in[8];
    const float* b2    = (const float*)d_in[9];
    const float* gamma = (const float*)d_in[10];
    const float* beta  = (const float*)d_in[11];
    const int*   ei    = (const int*)d_in[12];

    // ---- workspace layout ----
    char* base = (char*)d_ws;
    size_t off = 0;
    auto alloc = [&](size_t bytes) { void* p = base + off; off += (bytes + 15) & ~(size_t)15; return p; };
    _Float16* h16  = (_Float16*)alloc((size_t)NPAD * DD * 2);   // proj output (layer-0 input)
    _Float16* aggH = (_Float16*)alloc((size_t)NPAD * DD * 2);
    _Float16* z1H  = (_Float16*)alloc((size_t)NPAD * HH * 2);
    _Float16* z16  = (_Float16*)alloc((size_t)NPAD * DD * 2);   // raw GEMM2 output (pre-BN)
    _Float16* xH   = (_Float16*)alloc((size_t)NPAD * KX * 2);
    _Float16* WxT  = (_Float16*)alloc((size_t)DD * KX * 2);
    _Float16* W1T  = (_Float16*)alloc((size_t)LL * DD * HH * 2);
    _Float16* W2T  = (_Float16*)alloc((size_t)LL * DD * HH * 2);
    float*    s7   = (float*)   alloc((size_t)NN * 8 * 4);
    float*    sums = (float*)   alloc(256 * 4);
    int* counts    = (int*)alloc(50048 * 4);
    int* rowptr    = (int*)alloc(50056 * 4);
    int* cursor    = (int*)alloc(50048 * 4);
    int* blocksums = (int*)alloc(256 * 4);
    int* csr_src   = (int*)alloc((size_t)EE * 4);
    int* csr_eid   = (int*)alloc((size_t)EE * 4);
    if (ws_size < off) return;

    // ---- per-call zeroing ----
    hipMemsetAsync(counts, 0, 50048 * sizeof(int), stream);
    hipMemsetAsync(aggH + (size_t)NN * DD, 0, (size_t)(NPAD - NN) * DD * 2, stream); // pad rows

    // ---- prolog ----
    conv_x_kernel<<<(NPAD * KX + 255) / 256, 256, 0, stream>>>(x, xH);
    conv_wx_kernel<<<(DD * KX + 255) / 256, 256, 0, stream>>>(Wx, WxT);
    conv_w_kernel<<<(LL * DD * HH + 255) / 256, 256, 0, stream>>>(W1, W2, W1T, W2T);
    gemm_f16<KX, DD, 0, 0><<<dim3(NPAD / 128, DD / 64), 256, 0, stream>>>(
        xH, WxT, bx, h16, nullptr);
    count_kernel<<<(EE + 255) / 256, 256, 0, stream>>>(ei, counts);
    count_scan1<<<SCAN_BLOCKS, 256, 0, stream>>>(counts, rowptr, blocksums);
    count_scan2<<<1, 256, 0, stream>>>(blocksums, rowptr);
    count_scan3<<<SCAN_BLOCKS, 256, 0, stream>>>(blocksums, rowptr, cursor);
    csr_fill_kernel<<<(EE + 255) / 256, 256, 0, stream>>>(ei, cursor, csr_src, csr_eid);
    node_prep_kernel<<<(NN + 3) / 4, 256, 0, stream>>>(ea, rowptr, csr_eid, s7);

    // ---- layers ----
    for (int l = 0; l < LL; l++) {
        if (l == 0)
            aggregate_kernel<0><<<(NN + 3) / 4, 256, 0, stream>>>(
                h16, rowptr, csr_src, s7, We, be, nullptr, nullptr, nullptr, aggH);
        else
            aggregate_kernel<1><<<(NN + 3) / 4, 256, 0, stream>>>(
                z16, rowptr, csr_src, s7, We, be, sums,
                gamma + (size_t)(l - 1) * DD, beta + (size_t)(l - 1) * DD, aggH);
        gemm_f16<DD, HH, 1, 0><<<dim3(NPAD / 128, HH / 64), 256, 0, stream>>>(
            aggH, W1T + (size_t)l * DD * HH, b1 + (size_t)l * HH, z1H, nullptr);
        hipMemsetAsync(sums, 0, 256 * sizeof(float), stream);
        gemm_f16<HH, DD, 0, 1><<<dim3(NPAD / 128, DD / 64), 256, 0, stream>>>(
            z1H, W2T + (size_t)l * DD * HH, b2 + (size_t)l * DD, z16, sums);
    }
    bn_apply_kernel<<<(NN * 64 + 255) / 256, 256, 0, stream>>>(
        z16, sums, gamma + (size_t)(LL - 1) * DD, beta + (size_t)(LL - 1) * DD, (float*)d_out);
}